// Round 1
// baseline (3958.164 us; speedup 1.0000x reference)
//
#include <hip/hip_runtime.h>

// PhysicsRULModel fully-fused kernel for MI355X (gfx950).
// grid = B = 256 blocks (one batch per block, 1 block/CU), block = 256 threads.
// Thread t = LSTM gate t (type = t>>6 in {i,f,g,o}, unit j = t&63).
// LSTM weight rows in VGPRs; h state shared via LDS broadcast float4 reads.
// Pointwise MLP chain processed in CHUNK=8 step batches from an LDS ring.

#define Bn 256
#define Tn 2048
#define Hn 64
#define CH 8

__device__ __forceinline__ float rcpf_(float x) { return __builtin_amdgcn_rcpf(x); }
__device__ __forceinline__ float sigf_(float x) { return rcpf_(1.0f + __expf(-x)); }
// tanh(x) = 1 - 2/(e^{2x}+1): saturates correctly for |x| large (no NaN).
__device__ __forceinline__ float tanhf2_(float x) {
    float e = __expf(2.0f * x);
    return 1.0f - 2.0f * rcpf_(e + 1.0f);
}

#define DOT4(acc, w_, h_) acc += (w_).x*(h_).x + (w_).y*(h_).y + (w_).z*(h_).z + (w_).w*(h_).w

__global__ __launch_bounds__(256, 1)
void fused_rul_kernel(
    const float* __restrict__ ts,   const float* __restrict__ sf,
    const float* __restrict__ Wih0, const float* __restrict__ Whh0,
    const float* __restrict__ bih0, const float* __restrict__ bhh0,
    const float* __restrict__ Wih1, const float* __restrict__ Whh1,
    const float* __restrict__ bih1, const float* __restrict__ bhh1,
    const float* __restrict__ seW1, const float* __restrict__ seb1,
    const float* __restrict__ seW2, const float* __restrict__ seb2,
    const float* __restrict__ pbW1, const float* __restrict__ pbb1,
    const float* __restrict__ pbW2, const float* __restrict__ pbb2,
    const float* __restrict__ pbW3, const float* __restrict__ pbb3,
    const float* __restrict__ drW1, const float* __restrict__ drb1,
    const float* __restrict__ drW2, const float* __restrict__ drb2,
    const float* __restrict__ drW3, const float* __restrict__ drb3,
    const float* __restrict__ ruW1, const float* __restrict__ rub1,
    const float* __restrict__ ruW2, const float* __restrict__ rub2,
    float* __restrict__ out)
{
    const int tid  = threadIdx.x;
    const int b    = blockIdx.x;
    const int type = tid >> 6;   // 0:i 1:f 2:g 3:o  (wave-uniform)

    // ---- LDS ----
    __shared__ __align__(16) float h0s[Hn];
    __shared__ __align__(16) float h1s[Hn];
    __shared__ __align__(16) float gates[256];
    __shared__ __align__(16) float h1ring[CH][Hn];
    __shared__ float tempc[CH];
    __shared__ __align__(16) float ssb[CH][32];    // system_states
    __shared__ __align__(16) float se1b[CH][32];
    __shared__ __align__(16) float dr1b[CH][Hn];
    __shared__ float degb[CH];
    __shared__ float hltb[CH];
    // small-MLP weights, padded pitches (float4-aligned rows)
    __shared__ __align__(16) float seW1L[32 * 68];
    __shared__ __align__(16) float seW2L[32 * 36];
    __shared__ __align__(16) float drW1L[64 * 36];
    __shared__ __align__(16) float drW2L[32 * 68];
    __shared__ __align__(16) float ruW1L[32 * 36];
    __shared__ float seb1L[32], seb2L[32], drb1L[64], drb2L[32], drW3L[32];
    __shared__ float rub1L[32], ruW2L[32];
    __shared__ float phys_s[4];       // [A, -Ea*1000/R, Ea, logA]
    __shared__ float drb3_s, rub2_s;

    // ---- cooperative LDS weight staging (with pitch remap) ----
    for (int i = tid; i < 32 * 64; i += 256) { int r = i >> 6, c = i & 63; seW1L[r * 68 + c] = seW1[i]; }
    for (int i = tid; i < 32 * 32; i += 256) { int r = i >> 5, c = i & 31; seW2L[r * 36 + c] = seW2[i]; }
    for (int i = tid; i < 64 * 35; i += 256) { int r = i / 35, c = i % 35; drW1L[r * 36 + c] = drW1[i]; }
    for (int i = tid; i < 32 * 64; i += 256) { int r = i >> 6, c = i & 63; drW2L[r * 68 + c] = drW2[i]; }
    for (int i = tid; i < 32 * 33; i += 256) { int r = i / 33, c = i % 33; ruW1L[r * 36 + c] = ruW1[i]; }
    if (tid < 32) {
        seb1L[tid] = seb1[tid]; seb2L[tid] = seb2[tid]; drb2L[tid] = drb2[tid];
        drW3L[tid] = drW3[tid]; rub1L[tid] = rub1[tid]; ruW2L[tid] = ruW2[tid];
    }
    if (tid < 64) drb1L[tid] = drb1[tid];
    if (tid == 0) { drb3_s = drb3[0]; rub2_s = rub2[0]; }

    // ---- physics branch (tiny MLP, thread 0, once per block) ----
    if (tid == 0) {
        float p1[32];
        for (int o = 0; o < 32; ++o) {
            float a = pbb1[o];
            for (int k = 0; k < 3; ++k) a += pbW1[o * 3 + k] * sf[b * 3 + k];
            p1[o] = fmaxf(a, 0.f);
        }
        float p2[16];
        for (int o = 0; o < 16; ++o) {
            float a = pbb2[o];
            for (int k = 0; k < 32; ++k) a += pbW2[o * 32 + k] * p1[k];
            p2[o] = fmaxf(a, 0.f);
        }
        float Ea = pbb3[0], lA = pbb3[1];
        for (int k = 0; k < 16; ++k) { Ea += pbW3[k] * p2[k]; lA += pbW3[16 + k] * p2[k]; }
        phys_s[0] = __expf(lA);                 // A
        phys_s[1] = -Ea * 1000.0f / 8.314f;     // -EaJ/R
        phys_s[2] = Ea;
        phys_s[3] = lA;
    }

    // ---- LSTM weight rows into VGPRs (thread = gate row) ----
    float4 wh0v[16], wi1v[16], wh1v[16];
    {
        const float4* p0 = (const float4*)(Whh0 + tid * 64);
        const float4* p1 = (const float4*)(Wih1 + tid * 64);
        const float4* p2 = (const float4*)(Whh1 + tid * 64);
        #pragma unroll
        for (int k = 0; k < 16; ++k) { wh0v[k] = p0[k]; wi1v[k] = p1[k]; wh1v[k] = p2[k]; }
    }
    const float wi00 = Wih0[tid * 2 + 0], wi01 = Wih0[tid * 2 + 1];
    const float b0c = bih0[tid] + bhh0[tid];
    const float b1c = bih1[tid] + bhh1[tid];

    float c0r = 0.f, c1r = 0.f;   // cell state, threads 0..63
    float hst = 1.0f;             // health scan state, thread 0
    if (tid < 64) { h0s[tid] = 0.f; h1s[tid] = 0.f; }
    __syncthreads();

    const float* tsb  = ts + (size_t)b * Tn * 2;
    float* outR = out + (size_t)b * Tn;
    float* outD = out + (size_t)Bn * Tn + (size_t)b * Tn;
    float* outH = out + 2 * (size_t)Bn * Tn + (size_t)b * Tn;

    #pragma unroll 1
    for (int t0 = 0; t0 < Tn; t0 += CH) {
        // ================= LSTM: CH sequential steps =================
        #pragma unroll 1
        for (int cp = 0; cp < CH; ++cp) {
            const int t = t0 + cp;
            const float2 xv = *(const float2*)(tsb + 2 * t);

            // ---- layer 0 gates ----
            {
                float A0 = b0c + wi00 * xv.x + wi01 * xv.y;
                float A1 = 0.f, A2 = 0.f, A3 = 0.f;
                const float4* hv = (const float4*)h0s;
                #pragma unroll
                for (int k = 0; k < 16; k += 4) {
                    float4 h_;
                    h_ = hv[k + 0]; DOT4(A0, wh0v[k + 0], h_);
                    h_ = hv[k + 1]; DOT4(A1, wh0v[k + 1], h_);
                    h_ = hv[k + 2]; DOT4(A2, wh0v[k + 2], h_);
                    h_ = hv[k + 3]; DOT4(A3, wh0v[k + 3], h_);
                }
                float g = (A0 + A1) + (A2 + A3);
                g = (type == 2) ? tanhf2_(g) : sigf_(g);   // pre-transform gates
                gates[tid] = g;
            }
            __syncthreads();
            if (tid < 64) {
                float i_ = gates[tid], f_ = gates[64 + tid], g_ = gates[128 + tid], o_ = gates[192 + tid];
                c0r = f_ * c0r + i_ * g_;
                h0s[tid] = o_ * tanhf2_(c0r);
                if (tid == 0) tempc[cp] = xv.x;
            }
            __syncthreads();

            // ---- layer 1 gates ----
            {
                float A0 = b1c, A1 = 0.f, A2 = 0.f, A3 = 0.f;
                const float4* h0v4 = (const float4*)h0s;
                const float4* h1v4 = (const float4*)h1s;
                #pragma unroll
                for (int k = 0; k < 16; k += 4) {
                    float4 h_;
                    h_ = h0v4[k + 0]; DOT4(A0, wi1v[k + 0], h_);
                    h_ = h0v4[k + 1]; DOT4(A1, wi1v[k + 1], h_);
                    h_ = h0v4[k + 2]; DOT4(A2, wi1v[k + 2], h_);
                    h_ = h0v4[k + 3]; DOT4(A3, wi1v[k + 3], h_);
                    h_ = h1v4[k + 0]; DOT4(A0, wh1v[k + 0], h_);
                    h_ = h1v4[k + 1]; DOT4(A1, wh1v[k + 1], h_);
                    h_ = h1v4[k + 2]; DOT4(A2, wh1v[k + 2], h_);
                    h_ = h1v4[k + 3]; DOT4(A3, wh1v[k + 3], h_);
                }
                float g = (A0 + A1) + (A2 + A3);
                g = (type == 2) ? tanhf2_(g) : sigf_(g);
                gates[tid] = g;
            }
            __syncthreads();
            if (tid < 64) {
                float i_ = gates[tid], f_ = gates[64 + tid], g_ = gates[128 + tid], o_ = gates[192 + tid];
                c1r = f_ * c1r + i_ * g_;
                float hv = o_ * tanhf2_(c1r);
                h1s[tid] = hv;
                h1ring[cp][tid] = hv;
            }
            __syncthreads();
        }

        // ================= pointwise chain on the CH-step chunk =================
        // --- se1: relu(se_W1 @ h1 + b) ; thread=(pos,j) pos=tid>>5, j=tid&31
        {
            const int pos = tid >> 5, jj = tid & 31;
            float a = seb1L[jj];
            const float4* wr = (const float4*)&seW1L[jj * 68];
            const float4* hr = (const float4*)&h1ring[pos][0];
            #pragma unroll
            for (int k = 0; k < 16; ++k) { float4 w = wr[k], h = hr[k]; DOT4(a, w, h); }
            se1b[pos][jj] = fmaxf(a, 0.f);
        }
        __syncthreads();
        // --- se2: ss = se_W2 @ se1 + b (no relu)
        {
            const int pos = tid >> 5, jj = tid & 31;
            float a = seb2L[jj];
            const float4* wr = (const float4*)&seW2L[jj * 36];
            const float4* xr = (const float4*)&se1b[pos][0];
            #pragma unroll
            for (int k = 0; k < 8; ++k) { float4 w = wr[k], x = xr[k]; DOT4(a, w, x); }
            ssb[pos][jj] = a;
        }
        __syncthreads();
        // --- dr1: relu(dr_W1 @ [ss, temp, Ea, logA] + b), 64 outs x CH pos (2 reps)
        {
            const int jj = tid & 63;
            const float4* wr = (const float4*)&drW1L[jj * 36];
            const float w32 = drW1L[jj * 36 + 32], w33 = drW1L[jj * 36 + 33], w34 = drW1L[jj * 36 + 34];
            const float bb = drb1L[jj];
            const float ea_ = phys_s[2], la_ = phys_s[3];
            #pragma unroll
            for (int rep = 0; rep < 2; ++rep) {
                const int pos = (tid >> 6) + rep * 4;
                float a = bb;
                const float4* xr = (const float4*)&ssb[pos][0];
                #pragma unroll
                for (int k = 0; k < 8; ++k) { float4 w = wr[k], x = xr[k]; DOT4(a, w, x); }
                a += w32 * tempc[pos] + w33 * ea_ + w34 * la_;
                dr1b[pos][jj] = fmaxf(a, 0.f);
            }
        }
        __syncthreads();
        // --- dr2 + dr3 (fused reduce): deg = dr_W3 @ relu(dr_W2 @ dr1 + b) + b3
        {
            const int pos = tid >> 5, jj = tid & 31;
            float a = drb2L[jj];
            const float4* wr = (const float4*)&drW2L[jj * 68];
            const float4* xr = (const float4*)&dr1b[pos][0];
            #pragma unroll
            for (int k = 0; k < 16; ++k) { float4 w = wr[k], x = xr[k]; DOT4(a, w, x); }
            float p = drW3L[jj] * fmaxf(a, 0.f);
            #pragma unroll
            for (int off = 16; off > 0; off >>= 1) p += __shfl_down(p, off, 32);
            if (jj == 0) degb[pos] = p + drb3_s;
        }
        __syncthreads();
        // --- health scan (sequential, thread 0)
        if (tid == 0) {
            const float Af = phys_s[0], ne = phys_s[1];
            #pragma unroll
            for (int p2 = 0; p2 < CH; ++p2) {
                float tK  = tempc[p2] + 273.15f;
                float arr = Af * __expf(ne * rcpf_(tK));
                float comb = 0.7f * degb[p2] + 0.3f * arr;
                hst = fminf(fmaxf(hst - comb, 0.f), 1.f);
                hltb[p2] = hst;
            }
        }
        __syncthreads();
        // --- rul head (fused reduce) + outputs
        {
            const int pos = tid >> 5, jj = tid & 31;
            float a = rub1L[jj];
            const float4* wr = (const float4*)&ruW1L[jj * 36];
            const float4* xr = (const float4*)&ssb[pos][0];
            #pragma unroll
            for (int k = 0; k < 8; ++k) { float4 w = wr[k], x = xr[k]; DOT4(a, w, x); }
            a += ruW1L[jj * 36 + 32] * hltb[pos];
            float p = ruW2L[jj] * fmaxf(a, 0.f);
            #pragma unroll
            for (int off = 16; off > 0; off >>= 1) p += __shfl_down(p, off, 32);
            if (jj == 0) outR[t0 + pos] = fmaxf(p + rub2_s, 0.f);
        }
        if (tid < CH) { outD[t0 + tid] = degb[tid]; outH[t0 + tid] = hltb[tid]; }
    }
}

extern "C" void kernel_launch(void* const* d_in, const int* in_sizes, int n_in,
                              void* d_out, int out_size, void* d_ws, size_t ws_size,
                              hipStream_t stream) {
    const float* ts   = (const float*)d_in[0];
    const float* sf   = (const float*)d_in[1];
    const float* Wih0 = (const float*)d_in[2];
    const float* Whh0 = (const float*)d_in[3];
    const float* bih0 = (const float*)d_in[4];
    const float* bhh0 = (const float*)d_in[5];
    const float* Wih1 = (const float*)d_in[6];
    const float* Whh1 = (const float*)d_in[7];
    const float* bih1 = (const float*)d_in[8];
    const float* bhh1 = (const float*)d_in[9];
    const float* seW1 = (const float*)d_in[10];
    const float* seb1 = (const float*)d_in[11];
    const float* seW2 = (const float*)d_in[12];
    const float* seb2 = (const float*)d_in[13];
    const float* pbW1 = (const float*)d_in[14];
    const float* pbb1 = (const float*)d_in[15];
    const float* pbW2 = (const float*)d_in[16];
    const float* pbb2 = (const float*)d_in[17];
    const float* pbW3 = (const float*)d_in[18];
    const float* pbb3 = (const float*)d_in[19];
    const float* drW1 = (const float*)d_in[20];
    const float* drb1 = (const float*)d_in[21];
    const float* drW2 = (const float*)d_in[22];
    const float* drb2 = (const float*)d_in[23];
    const float* drW3 = (const float*)d_in[24];
    const float* drb3 = (const float*)d_in[25];
    const float* ruW1 = (const float*)d_in[26];
    const float* rub1 = (const float*)d_in[27];
    const float* ruW2 = (const float*)d_in[28];
    const float* rub2 = (const float*)d_in[29];
    float* out = (float*)d_out;

    fused_rul_kernel<<<dim3(Bn), dim3(256), 0, stream>>>(
        ts, sf, Wih0, Whh0, bih0, bhh0, Wih1, Whh1, bih1, bhh1,
        seW1, seb1, seW2, seb2, pbW1, pbb1, pbW2, pbb2, pbW3, pbb3,
        drW1, drb1, drW2, drb2, drW3, drb3, ruW1, rub1, ruW2, rub2, out);
}

// Round 3
// 2291.368 us; speedup vs baseline: 1.7274x; 1.7274x over previous
//
#include <hip/hip_runtime.h>

// PhysicsRULModel fully-fused kernel for MI355X (gfx950).  R2 = R1 + tempc fix.
// grid = B = 256 blocks (1 block/CU), block = 512 threads (8 waves/CU).
// Thread = (gate row r = tid>>1, half hf = tid&1): holds HALF weight rows
// (24 float4 = 96 VGPRs -> no scratch spills, unlike R0's 192).
// Software-pipelined: phase A computes gates0(t) AND gates1(t-1) together
// (both depend only on h0(t-1), h1(t-2)); phase B updates both layers'
// states on different waves. 2 barriers/step instead of 4.
// Pointwise MLP chain processed in CH=16 step chunks from an LDS ring.
// R2 fix: tempc[last] must be written at u==Tn (was gated by u<Tn, so the
// final chunk's position-15 temperature was stale -> absmax 0.096 @ t=2047).

#define Bn 256
#define Tn 2048
#define Hn 64
#define CH 16
#define NT 512

__device__ __forceinline__ float rcpf_(float x) { return __builtin_amdgcn_rcpf(x); }
__device__ __forceinline__ float sigf_(float x) { return rcpf_(1.0f + __expf(-x)); }
// tanh(x) = 1 - 2/(e^{2x}+1): saturates correctly for |x| large (no NaN).
__device__ __forceinline__ float tanhf2_(float x) {
    float e = __expf(2.0f * x);
    return 1.0f - 2.0f * rcpf_(e + 1.0f);
}

#define DOT4(acc, w_, h_) acc += (w_).x*(h_).x + (w_).y*(h_).y + (w_).z*(h_).z + (w_).w*(h_).w

__global__ __launch_bounds__(512, 1)
void fused_rul_kernel(
    const float* __restrict__ ts,   const float* __restrict__ sf,
    const float* __restrict__ Wih0, const float* __restrict__ Whh0,
    const float* __restrict__ bih0, const float* __restrict__ bhh0,
    const float* __restrict__ Wih1, const float* __restrict__ Whh1,
    const float* __restrict__ bih1, const float* __restrict__ bhh1,
    const float* __restrict__ seW1, const float* __restrict__ seb1,
    const float* __restrict__ seW2, const float* __restrict__ seb2,
    const float* __restrict__ pbW1, const float* __restrict__ pbb1,
    const float* __restrict__ pbW2, const float* __restrict__ pbb2,
    const float* __restrict__ pbW3, const float* __restrict__ pbb3,
    const float* __restrict__ drW1, const float* __restrict__ drb1,
    const float* __restrict__ drW2, const float* __restrict__ drb2,
    const float* __restrict__ drW3, const float* __restrict__ drb3,
    const float* __restrict__ ruW1, const float* __restrict__ rub1,
    const float* __restrict__ ruW2, const float* __restrict__ rub2,
    float* __restrict__ out)
{
    const int tid = threadIdx.x;
    const int b   = blockIdx.x;
    const int r   = tid >> 1;        // gate row 0..255
    const int hf  = tid & 1;         // half 0/1
    const int type = r >> 6;         // 0:i 1:f 2:g 3:o

    // ---- LDS ----
    __shared__ __align__(16) float h0s[Hn];
    __shared__ __align__(16) float h1s[Hn];
    __shared__ __align__(16) float gates0[256];
    __shared__ __align__(16) float gates1[256];
    __shared__ __align__(16) float h1ring[CH][Hn];
    __shared__ float tempc[CH];
    __shared__ __align__(16) float ssb[CH][32];    // system_states
    __shared__ __align__(16) float se1b[CH][32];
    __shared__ __align__(16) float dr1b[CH][Hn];
    __shared__ float degb[CH];
    __shared__ float hltb[CH];
    // small-MLP weights, padded pitches (float4-aligned rows)
    __shared__ __align__(16) float seW1L[32 * 68];
    __shared__ __align__(16) float seW2L[32 * 36];
    __shared__ __align__(16) float drW1L[64 * 36];
    __shared__ __align__(16) float drW2L[32 * 68];
    __shared__ __align__(16) float ruW1L[32 * 36];
    __shared__ float seb1L[32], seb2L[32], drb1L[64], drb2L[32], drW3L[32];
    __shared__ float rub1L[32], ruW2L[32];
    __shared__ float phys_s[4];       // [A, -Ea*1000/R, Ea, logA]
    __shared__ float drb3_s, rub2_s;

    // ---- cooperative LDS weight staging (with pitch remap) ----
    for (int i = tid; i < 32 * 64; i += NT) { int rr = i >> 6, c = i & 63; seW1L[rr * 68 + c] = seW1[i]; }
    for (int i = tid; i < 32 * 32; i += NT) { int rr = i >> 5, c = i & 31; seW2L[rr * 36 + c] = seW2[i]; }
    for (int i = tid; i < 64 * 35; i += NT) { int rr = i / 35, c = i % 35; drW1L[rr * 36 + c] = drW1[i]; }
    for (int i = tid; i < 32 * 64; i += NT) { int rr = i >> 6, c = i & 63; drW2L[rr * 68 + c] = drW2[i]; }
    for (int i = tid; i < 32 * 33; i += NT) { int rr = i / 33, c = i % 33; ruW1L[rr * 36 + c] = ruW1[i]; }
    if (tid < 32) {
        seb1L[tid] = seb1[tid]; seb2L[tid] = seb2[tid]; drb2L[tid] = drb2[tid];
        drW3L[tid] = drW3[tid]; rub1L[tid] = rub1[tid]; ruW2L[tid] = ruW2[tid];
    }
    if (tid < 64) drb1L[tid] = drb1[tid];
    if (tid == 0) { drb3_s = drb3[0]; rub2_s = rub2[0]; }

    // ---- physics branch (tiny MLP, thread 0, once per block) ----
    if (tid == 0) {
        float p1[32];
        for (int o = 0; o < 32; ++o) {
            float a = pbb1[o];
            for (int k = 0; k < 3; ++k) a += pbW1[o * 3 + k] * sf[b * 3 + k];
            p1[o] = fmaxf(a, 0.f);
        }
        float p2[16];
        for (int o = 0; o < 16; ++o) {
            float a = pbb2[o];
            for (int k = 0; k < 32; ++k) a += pbW2[o * 32 + k] * p1[k];
            p2[o] = fmaxf(a, 0.f);
        }
        float Ea = pbb3[0], lA = pbb3[1];
        for (int k = 0; k < 16; ++k) { Ea += pbW3[k] * p2[k]; lA += pbW3[16 + k] * p2[k]; }
        phys_s[0] = __expf(lA);                 // A
        phys_s[1] = -Ea * 1000.0f / 8.314f;     // -EaJ/R
        phys_s[2] = Ea;
        phys_s[3] = lA;
    }

    // ---- LSTM half weight rows into VGPRs ----
    float4 wh0h[8], wi1h[8], wh1h[8];
    {
        const float4* p0 = (const float4*)(Whh0 + r * 64 + (hf << 5));
        const float4* p1 = (const float4*)(Wih1 + r * 64 + (hf << 5));
        const float4* p2 = (const float4*)(Whh1 + r * 64 + (hf << 5));
        #pragma unroll
        for (int k = 0; k < 8; ++k) { wh0h[k] = p0[k]; wi1h[k] = p1[k]; wh1h[k] = p2[k]; }
    }
    const float wi0a = Wih0[r * 2 + 0], wi0b = Wih0[r * 2 + 1];
    const float b0r = bih0[r] + bhh0[r];
    const float b1r = bih1[r] + bhh1[r];

    float c0 = 0.f, c1 = 0.f;     // cell states: c0 on tids 0..63, c1 on tids 64..127
    float hst = 1.0f;             // health scan state, thread 0
    float xprev = 0.f;
    if (tid < 64) { h0s[tid] = 0.f; h1s[tid] = 0.f; }
    __syncthreads();

    const float* tsb  = ts + (size_t)b * Tn * 2;
    float* outR = out + (size_t)b * Tn;
    float* outD = out + (size_t)Bn * Tn + (size_t)b * Tn;
    float* outH = out + 2 * (size_t)Bn * Tn + (size_t)b * Tn;

    // Pipelined loop: iteration u computes gates0(u) [if u<Tn] and
    // gates1(u-1) [if u>=1] in one phase, updates both states in phase B.
    #pragma unroll 1
    for (int u = 0; u <= Tn; ++u) {
        float2 xv = make_float2(0.f, 0.f);
        if (u < Tn) xv = *(const float2*)(tsb + 2 * u);

        // ---------- phase A: both gate dot-products (half rows) ----------
        {
            float a0 = 0.f, a1 = 0.f, a1b = 0.f;
            if (!hf) { a0 = b0r + wi0a * xv.x + wi0b * xv.y; a1 = b1r; }
            const float4* h0v = (const float4*)(h0s + (hf << 5));
            const float4* h1v = (const float4*)(h1s + (hf << 5));
            #pragma unroll
            for (int k = 0; k < 8; ++k) {
                float4 h0k = h0v[k];
                DOT4(a0, wh0h[k], h0k);      // layer0 gate
                DOT4(a1, wi1h[k], h0k);      // layer1 input-to-hidden (x = h0)
                float4 h1k = h1v[k];
                DOT4(a1b, wh1h[k], h1k);     // layer1 hidden-to-hidden
            }
            a1 += a1b;
            a0 += __shfl_xor(a0, 1);
            a1 += __shfl_xor(a1, 1);
            // split the activation across the pair: hf=0 handles gate0, hf=1 gate1
            float val = hf ? a1 : a0;
            float act = (type == 2) ? tanhf2_(val) : sigf_(val);
            if (!hf) { if (u < Tn) gates0[r] = act; }
            else     { if (u >= 1) gates1[r] = act; }
        }
        __syncthreads();

        // ---------- phase B: state updates (wave0 = layer0, wave1 = layer1) ----------
        if (tid == 0 && u >= 1) tempc[(u - 1) & (CH - 1)] = xprev;   // R2 fix: not gated by u<Tn
        if (tid < 64) {
            if (u < Tn) {
                float i_ = gates0[tid], f_ = gates0[64 + tid], g_ = gates0[128 + tid], o_ = gates0[192 + tid];
                c0 = f_ * c0 + i_ * g_;
                h0s[tid] = o_ * tanhf2_(c0);
            }
        } else if (tid < 128) {
            if (u >= 1) {
                int j = tid - 64;
                float i_ = gates1[j], f_ = gates1[64 + j], g_ = gates1[128 + j], o_ = gates1[192 + j];
                c1 = f_ * c1 + i_ * g_;
                float hv = o_ * tanhf2_(c1);
                h1s[j] = hv;
                h1ring[(u - 1) & (CH - 1)][j] = hv;
            }
        }
        xprev = xv.x;
        __syncthreads();

        // ---------- pointwise chain on completed CH-step chunk ----------
        if ((u & (CH - 1)) == 0 && u > 0) {
            const int t0 = u - CH;
            // --- se1: relu(se_W1 @ h1 + b); pos=tid>>5 (16), jj=tid&31
            {
                const int pos = tid >> 5, jj = tid & 31;
                float a = seb1L[jj];
                const float4* wr = (const float4*)&seW1L[jj * 68];
                const float4* hr = (const float4*)&h1ring[pos][0];
                #pragma unroll
                for (int k = 0; k < 16; ++k) { float4 w = wr[k], h = hr[k]; DOT4(a, w, h); }
                se1b[pos][jj] = fmaxf(a, 0.f);
            }
            __syncthreads();
            // --- se2: ss = se_W2 @ se1 + b (no relu)
            {
                const int pos = tid >> 5, jj = tid & 31;
                float a = seb2L[jj];
                const float4* wr = (const float4*)&seW2L[jj * 36];
                const float4* xr = (const float4*)&se1b[pos][0];
                #pragma unroll
                for (int k = 0; k < 8; ++k) { float4 w = wr[k], x = xr[k]; DOT4(a, w, x); }
                ssb[pos][jj] = a;
            }
            __syncthreads();
            // --- dr1: relu(dr_W1 @ [ss, temp, Ea, logA] + b); 64 out x 16 pos, 2 reps
            {
                const int jj = tid & 63;
                const float4* wr = (const float4*)&drW1L[jj * 36];
                const float w32 = drW1L[jj * 36 + 32], w33 = drW1L[jj * 36 + 33], w34 = drW1L[jj * 36 + 34];
                const float bb = drb1L[jj];
                const float ea_ = phys_s[2], la_ = phys_s[3];
                #pragma unroll
                for (int rep = 0; rep < 2; ++rep) {
                    const int pos = (tid >> 6) + rep * 8;
                    float a = bb;
                    const float4* xr = (const float4*)&ssb[pos][0];
                    #pragma unroll
                    for (int k = 0; k < 8; ++k) { float4 w = wr[k], x = xr[k]; DOT4(a, w, x); }
                    a += w32 * tempc[pos] + w33 * ea_ + w34 * la_;
                    dr1b[pos][jj] = fmaxf(a, 0.f);
                }
            }
            __syncthreads();
            // --- dr2 + dr3 (fused reduce): deg = dr_W3 @ relu(dr_W2 @ dr1 + b) + b3
            {
                const int pos = tid >> 5, jj = tid & 31;
                float a = drb2L[jj];
                const float4* wr = (const float4*)&drW2L[jj * 68];
                const float4* xr = (const float4*)&dr1b[pos][0];
                #pragma unroll
                for (int k = 0; k < 16; ++k) { float4 w = wr[k], x = xr[k]; DOT4(a, w, x); }
                float p = drW3L[jj] * fmaxf(a, 0.f);
                #pragma unroll
                for (int off = 16; off > 0; off >>= 1) p += __shfl_down(p, off, 32);
                if (jj == 0) degb[pos] = p + drb3_s;
            }
            __syncthreads();
            // --- health scan (sequential, thread 0)
            if (tid == 0) {
                const float Af = phys_s[0], ne = phys_s[1];
                #pragma unroll
                for (int p2 = 0; p2 < CH; ++p2) {
                    float tK  = tempc[p2] + 273.15f;
                    float arr = Af * __expf(ne * rcpf_(tK));
                    float comb = 0.7f * degb[p2] + 0.3f * arr;
                    hst = fminf(fmaxf(hst - comb, 0.f), 1.f);
                    hltb[p2] = hst;
                }
            }
            __syncthreads();
            // --- rul head (fused reduce) + outputs
            {
                const int pos = tid >> 5, jj = tid & 31;
                float a = rub1L[jj];
                const float4* wr = (const float4*)&ruW1L[jj * 36];
                const float4* xr = (const float4*)&ssb[pos][0];
                #pragma unroll
                for (int k = 0; k < 8; ++k) { float4 w = wr[k], x = xr[k]; DOT4(a, w, x); }
                a += ruW1L[jj * 36 + 32] * hltb[pos];
                float p = ruW2L[jj] * fmaxf(a, 0.f);
                #pragma unroll
                for (int off = 16; off > 0; off >>= 1) p += __shfl_down(p, off, 32);
                if (jj == 0) outR[t0 + pos] = fmaxf(p + rub2_s, 0.f);
            }
            if (tid < CH) { outD[t0 + tid] = degb[tid]; outH[t0 + tid] = hltb[tid]; }
        }
    }
}

extern "C" void kernel_launch(void* const* d_in, const int* in_sizes, int n_in,
                              void* d_out, int out_size, void* d_ws, size_t ws_size,
                              hipStream_t stream) {
    const float* ts   = (const float*)d_in[0];
    const float* sf   = (const float*)d_in[1];
    const float* Wih0 = (const float*)d_in[2];
    const float* Whh0 = (const float*)d_in[3];
    const float* bih0 = (const float*)d_in[4];
    const float* bhh0 = (const float*)d_in[5];
    const float* Wih1 = (const float*)d_in[6];
    const float* Whh1 = (const float*)d_in[7];
    const float* bih1 = (const float*)d_in[8];
    const float* bhh1 = (const float*)d_in[9];
    const float* seW1 = (const float*)d_in[10];
    const float* seb1 = (const float*)d_in[11];
    const float* seW2 = (const float*)d_in[12];
    const float* seb2 = (const float*)d_in[13];
    const float* pbW1 = (const float*)d_in[14];
    const float* pbb1 = (const float*)d_in[15];
    const float* pbW2 = (const float*)d_in[16];
    const float* pbb2 = (const float*)d_in[17];
    const float* pbW3 = (const float*)d_in[18];
    const float* pbb3 = (const float*)d_in[19];
    const float* drW1 = (const float*)d_in[20];
    const float* drb1 = (const float*)d_in[21];
    const float* drW2 = (const float*)d_in[22];
    const float* drb2 = (const float*)d_in[23];
    const float* drW3 = (const float*)d_in[24];
    const float* drb3 = (const float*)d_in[25];
    const float* ruW1 = (const float*)d_in[26];
    const float* rub1 = (const float*)d_in[27];
    const float* ruW2 = (const float*)d_in[28];
    const float* rub2 = (const float*)d_in[29];
    float* out = (float*)d_out;

    fused_rul_kernel<<<dim3(Bn), dim3(NT), 0, stream>>>(
        ts, sf, Wih0, Whh0, bih0, bhh0, Wih1, Whh1, bih1, bhh1,
        seW1, seb1, seW2, seb2, pbW1, pbb1, pbW2, pbb2, pbW3, pbb3,
        drW1, drb1, drW2, drb2, drW3, drb3, ruW1, rub1, ruW2, rub2, out);
}

// Round 4
// 2212.819 us; speedup vs baseline: 1.7887x; 1.0355x over previous
//
#include <hip/hip_runtime.h>

// PhysicsRULModel fully-fused kernel for MI355X (gfx950).  R3.
// grid = B = 256 blocks (1 block/CU), block = 512 threads (8 waves/CU).
// ONE barrier per LSTM step (R2 had 2):
//   - wave w owns units 8w..8w+7; 8 lanes/unit = (gate g 0..3, half hf 0..1)
//   - each lane: half-row dots for layer0(t) + layer1(t-1)  (1-step skew)
//   - halves combined via shfl_xor(1); activation in-register;
//     all 4 activated gates gathered via static ds_swizzle (base|2k);
//     c0/c1 updated redundantly in all 8 lanes of the unit.
//   - h0s/h1s DOUBLE-BUFFERED -> read-buf != write-buf -> single barrier legal.
// Epilogue (MLP chain) at u==1 (mod 16): weight tables at pitch 66/34
// (== 2 mod 32 -> 2-way bank aliasing = free; R2's 68/36 gave 4-way conflicts,
// SQ_LDS_BANK_CONFLICT 7.3e7), float2 dots, tail columns in stride-1 arrays.

#define Bn 256
#define Tn 2048
#define Hn 64
#define CH 16
#define NT 512

__device__ __forceinline__ float rcpf_(float x) { return __builtin_amdgcn_rcpf(x); }
// tanh(x) = 1 - 2/(e^{2x}+1): saturates correctly for |x| large (no NaN).
__device__ __forceinline__ float tanhf2_(float x) {
    float e = __expf(2.0f * x);
    return 1.0f - 2.0f * rcpf_(e + 1.0f);
}
#define SWZ(v, imm) __int_as_float(__builtin_amdgcn_ds_swizzle(__float_as_int(v), imm))
#define DOT2(acc, w_, x_) { acc.x = fmaf((w_).x, (x_).x, acc.x); acc.y = fmaf((w_).y, (x_).y, acc.y); }

__global__ __launch_bounds__(512, 1)
void fused_rul_kernel(
    const float* __restrict__ ts,   const float* __restrict__ sf,
    const float* __restrict__ Wih0, const float* __restrict__ Whh0,
    const float* __restrict__ bih0, const float* __restrict__ bhh0,
    const float* __restrict__ Wih1, const float* __restrict__ Whh1,
    const float* __restrict__ bih1, const float* __restrict__ bhh1,
    const float* __restrict__ seW1, const float* __restrict__ seb1,
    const float* __restrict__ seW2, const float* __restrict__ seb2,
    const float* __restrict__ pbW1, const float* __restrict__ pbb1,
    const float* __restrict__ pbW2, const float* __restrict__ pbb2,
    const float* __restrict__ pbW3, const float* __restrict__ pbb3,
    const float* __restrict__ drW1, const float* __restrict__ drb1,
    const float* __restrict__ drW2, const float* __restrict__ drb2,
    const float* __restrict__ drW3, const float* __restrict__ drb3,
    const float* __restrict__ ruW1, const float* __restrict__ rub1,
    const float* __restrict__ ruW2, const float* __restrict__ rub2,
    float* __restrict__ out)
{
    const int tid = threadIdx.x;
    const int b   = blockIdx.x;
    // unit-grouped lane mapping
    const int j  = ((tid >> 6) << 3) + ((tid & 63) >> 3);  // unit 0..63
    const int m  = tid & 7;                                 // role within unit
    const int hf = m & 1;                                   // half 0/1
    const int g  = m >> 1;                                  // gate 0:i 1:f 2:g 3:o
    const int r  = (g << 6) + j;                            // gate row (both layers)

    // ---- LDS ----
    __shared__ __align__(16) float h0s[2][Hn];   // double-buffered states
    __shared__ __align__(16) float h1s[2][Hn];
    __shared__ __align__(16) float h1ring[CH][Hn];
    __shared__ float tempc[CH];
    __shared__ __align__(16) float ssb[CH][32];
    __shared__ __align__(16) float se1b[CH][32];
    __shared__ __align__(16) float dr1b[CH][Hn];
    __shared__ float degb[CH];
    __shared__ float hltb[CH];
    // MLP weight tables: pitch == 2 (mod 32) -> conflict-free float2 reads
    __shared__ __align__(16) float seW1L[32 * 66];
    __shared__ __align__(16) float seW2L[32 * 34];
    __shared__ __align__(16) float drW1L[64 * 34];
    __shared__ __align__(8)  float drW1t[3][64];   // cols 32..34 (temp, Ea, logA)
    __shared__ __align__(16) float drW2L[32 * 66];
    __shared__ __align__(16) float ruW1L[32 * 34];
    __shared__ float ruW1t[32];                    // col 32 (health)
    __shared__ float seb1L[32], seb2L[32], drb1L[64], drb2L[32], drW3L[32];
    __shared__ float rub1L[32], ruW2L[32];
    __shared__ float phys_s[4];       // [A, -Ea*1000/R, Ea, logA]
    __shared__ float drb3_s, rub2_s;

    // ---- cooperative LDS weight staging (pitch remap) ----
    for (int i = tid; i < 32 * 64; i += NT) { int rr = i >> 6, c = i & 63; seW1L[rr * 66 + c] = seW1[i]; }
    for (int i = tid; i < 32 * 32; i += NT) { int rr = i >> 5, c = i & 31; seW2L[rr * 34 + c] = seW2[i]; }
    for (int i = tid; i < 64 * 32; i += NT) { int rr = i >> 5, c = i & 31; drW1L[rr * 34 + c] = drW1[rr * 35 + c]; }
    if (tid < 192) { int k = tid >> 6, rr = tid & 63; drW1t[k][rr] = drW1[rr * 35 + 32 + k]; }
    for (int i = tid; i < 32 * 64; i += NT) { int rr = i >> 6, c = i & 63; drW2L[rr * 66 + c] = drW2[i]; }
    for (int i = tid; i < 32 * 32; i += NT) { int rr = i >> 5, c = i & 31; ruW1L[rr * 34 + c] = ruW1[rr * 33 + c]; }
    if (tid < 32) {
        ruW1t[tid] = ruW1[tid * 33 + 32];
        seb1L[tid] = seb1[tid]; seb2L[tid] = seb2[tid]; drb2L[tid] = drb2[tid];
        drW3L[tid] = drW3[tid]; rub1L[tid] = rub1[tid]; ruW2L[tid] = ruW2[tid];
    }
    if (tid < 64) drb1L[tid] = drb1[tid];
    if (tid == 0) { drb3_s = drb3[0]; rub2_s = rub2[0]; }

    // ---- physics branch (tiny MLP, thread 0, once per block) ----
    if (tid == 0) {
        float p1[32];
        for (int o = 0; o < 32; ++o) {
            float a = pbb1[o];
            for (int k = 0; k < 3; ++k) a += pbW1[o * 3 + k] * sf[b * 3 + k];
            p1[o] = fmaxf(a, 0.f);
        }
        float p2[16];
        for (int o = 0; o < 16; ++o) {
            float a = pbb2[o];
            for (int k = 0; k < 32; ++k) a += pbW2[o * 32 + k] * p1[k];
            p2[o] = fmaxf(a, 0.f);
        }
        float Ea = pbb3[0], lA = pbb3[1];
        for (int k = 0; k < 16; ++k) { Ea += pbW3[k] * p2[k]; lA += pbW3[16 + k] * p2[k]; }
        phys_s[0] = __expf(lA);                 // A
        phys_s[1] = -Ea * 1000.0f / 8.314f;     // -EaJ/R
        phys_s[2] = Ea;
        phys_s[3] = lA;
    }

    // ---- LSTM half weight rows into VGPRs (row r, half hf) ----
    float4 wh0h[8], wi1h[8], wh1h[8];
    {
        const float4* p0 = (const float4*)(Whh0 + r * 64 + (hf << 5));
        const float4* p1 = (const float4*)(Wih1 + r * 64 + (hf << 5));
        const float4* p2 = (const float4*)(Whh1 + r * 64 + (hf << 5));
        #pragma unroll
        for (int k = 0; k < 8; ++k) { wh0h[k] = p0[k]; wi1h[k] = p1[k]; wh1h[k] = p2[k]; }
    }
    const float wi0a = Wih0[r * 2 + 0], wi0b = Wih0[r * 2 + 1];
    const float b0r = bih0[r] + bhh0[r];
    const float b1r = bih1[r] + bhh1[r];
    // unified activation constants: sig(x)=rcp(1+e^-x); tanh(x)=1-2*rcp(1+e^2x)
    const bool  isg  = (g == 2);
    const float kmul = isg ? 2.f : -1.f;
    const float kk   = isg ? -2.f : 1.f;
    const float cc   = isg ? 1.f : 0.f;

    float c0 = 0.f, c1 = 0.f;     // cell state for unit j (replicated in 8 lanes)
    float hst = 1.0f;             // health scan state, thread 0
    float xprev = 0.f;
    if (tid < 64) { h0s[0][tid] = 0.f; h0s[1][tid] = 0.f; h1s[0][tid] = 0.f; h1s[1][tid] = 0.f; }
    __syncthreads();

    const float* tsb  = ts + (size_t)b * Tn * 2;
    float* outR = out + (size_t)b * Tn;
    float* outD = out + (size_t)Bn * Tn + (size_t)b * Tn;
    float* outH = out + 2 * (size_t)Bn * Tn + (size_t)b * Tn;

    // iteration u: layer0(u) [u<Tn] + layer1(u-1) [u>=1]; epilogue covers
    // positions [u-17, u-2] when u==1 (mod 16), u>16 (h1(t) lands at iter t+1).
    #pragma unroll 1
    for (int u = 0; u <= Tn + 1; ++u) {
        float2 xv = make_float2(0.f, 0.f);
        if (u < Tn) xv = *(const float2*)(tsb + 2 * u);

        // ---------- epilogue for completed chunk ----------
        if ((u & (CH - 1)) == 1 && u > 16) {
            const int t0 = u - 17;
            // --- se1: relu(se_W1 @ h1 + b); pos=tid>>5, jj=tid&31
            {
                const int pos = tid >> 5, jj = tid & 31;
                float2 acc = make_float2(0.f, 0.f);
                const float2* wr = (const float2*)(seW1L + jj * 66);
                const float2* hr = (const float2*)(&h1ring[pos][0]);
                #pragma unroll
                for (int k = 0; k < 32; ++k) { float2 w = wr[k], h = hr[k]; DOT2(acc, w, h); }
                se1b[pos][jj] = fmaxf(acc.x + acc.y + seb1L[jj], 0.f);
            }
            __syncthreads();
            // --- se2: ss = se_W2 @ se1 + b (no relu)
            {
                const int pos = tid >> 5, jj = tid & 31;
                float2 acc = make_float2(0.f, 0.f);
                const float2* wr = (const float2*)(seW2L + jj * 34);
                const float2* xr = (const float2*)(&se1b[pos][0]);
                #pragma unroll
                for (int k = 0; k < 16; ++k) { float2 w = wr[k], x = xr[k]; DOT2(acc, w, x); }
                ssb[pos][jj] = acc.x + acc.y + seb2L[jj];
            }
            __syncthreads();
            // --- dr1: relu(dr_W1 @ [ss, temp, Ea, logA] + b); 64 out x 16 pos
            {
                const int jj = tid & 63;
                const float2* wr = (const float2*)(drW1L + jj * 34);
                const float w32 = drW1t[0][jj], w33 = drW1t[1][jj], w34 = drW1t[2][jj];
                const float bb = drb1L[jj];
                const float ea_ = phys_s[2], la_ = phys_s[3];
                #pragma unroll
                for (int rep = 0; rep < 2; ++rep) {
                    const int pos = (tid >> 6) + rep * 8;
                    float2 acc = make_float2(0.f, 0.f);
                    const float2* xr = (const float2*)(&ssb[pos][0]);
                    #pragma unroll
                    for (int k = 0; k < 16; ++k) { float2 w = wr[k], x = xr[k]; DOT2(acc, w, x); }
                    float a = acc.x + acc.y + bb + w32 * tempc[pos] + w33 * ea_ + w34 * la_;
                    dr1b[pos][jj] = fmaxf(a, 0.f);
                }
            }
            __syncthreads();
            // --- dr2 + dr3 (fused reduce): deg = dr_W3 @ relu(dr_W2 @ dr1 + b) + b3
            {
                const int pos = tid >> 5, jj = tid & 31;
                float2 acc = make_float2(0.f, 0.f);
                const float2* wr = (const float2*)(drW2L + jj * 66);
                const float2* xr = (const float2*)(&dr1b[pos][0]);
                #pragma unroll
                for (int k = 0; k < 32; ++k) { float2 w = wr[k], x = xr[k]; DOT2(acc, w, x); }
                float p = drW3L[jj] * fmaxf(acc.x + acc.y + drb2L[jj], 0.f);
                #pragma unroll
                for (int off = 16; off > 0; off >>= 1) p += __shfl_down(p, off, 32);
                if (jj == 0) degb[pos] = p + drb3_s;
            }
            __syncthreads();
            // --- health scan (sequential, thread 0)
            if (tid == 0) {
                const float Af = phys_s[0], ne = phys_s[1];
                #pragma unroll
                for (int p2 = 0; p2 < CH; ++p2) {
                    float tK  = tempc[p2] + 273.15f;
                    float arr = Af * __expf(ne * rcpf_(tK));
                    float comb = 0.7f * degb[p2] + 0.3f * arr;
                    hst = fminf(fmaxf(hst - comb, 0.f), 1.f);
                    hltb[p2] = hst;
                }
            }
            __syncthreads();
            // --- rul head (fused reduce) + outputs
            {
                const int pos = tid >> 5, jj = tid & 31;
                float2 acc = make_float2(0.f, 0.f);
                const float2* wr = (const float2*)(ruW1L + jj * 34);
                const float2* xr = (const float2*)(&ssb[pos][0]);
                #pragma unroll
                for (int k = 0; k < 16; ++k) { float2 w = wr[k], x = xr[k]; DOT2(acc, w, x); }
                float a = acc.x + acc.y + rub1L[jj] + ruW1t[jj] * hltb[pos];
                float p = ruW2L[jj] * fmaxf(a, 0.f);
                #pragma unroll
                for (int off = 16; off > 0; off >>= 1) p += __shfl_down(p, off, 32);
                if (jj == 0) outR[t0 + pos] = fmaxf(p + rub2_s, 0.f);
            }
            if (tid < CH) { outD[t0 + tid] = degb[tid]; outH[t0 + tid] = hltb[tid]; }
        }

        // ---------- LSTM step (single phase, no internal barrier) ----------
        if (u <= Tn) {
            const int par = u & 1;
            const float* h0rd = &h0s[par ^ 1][0];   // h0(u-1)
            const float* h1rd = &h1s[par][0];       // h1(u-2)
            float2 A0 = make_float2(0.f, 0.f), A1 = make_float2(0.f, 0.f), A1b = make_float2(0.f, 0.f);
            const float4* h0v4 = (const float4*)(h0rd + (hf << 5));
            const float4* h1v4 = (const float4*)(h1rd + (hf << 5));
            #pragma unroll
            for (int k = 0; k < 8; ++k) {
                float4 h0k = h0v4[k];
                float2 hxy = make_float2(h0k.x, h0k.y), hzw = make_float2(h0k.z, h0k.w);
                float2 wxy = make_float2(wh0h[k].x, wh0h[k].y), wzw = make_float2(wh0h[k].z, wh0h[k].w);
                DOT2(A0, wxy, hxy); DOT2(A0, wzw, hzw);
                wxy = make_float2(wi1h[k].x, wi1h[k].y); wzw = make_float2(wi1h[k].z, wi1h[k].w);
                DOT2(A1, wxy, hxy); DOT2(A1, wzw, hzw);
                float4 h1k = h1v4[k];
                hxy = make_float2(h1k.x, h1k.y); hzw = make_float2(h1k.z, h1k.w);
                wxy = make_float2(wh1h[k].x, wh1h[k].y); wzw = make_float2(wh1h[k].z, wh1h[k].w);
                DOT2(A1b, wxy, hxy); DOT2(A1b, wzw, hzw);
            }
            float a0 = A0.x + A0.y;
            float a1 = (A1.x + A1b.x) + (A1.y + A1b.y);
            a0 += __shfl_xor(a0, 1);
            a1 += __shfl_xor(a1, 1);
            a0 = fmaf(wi0a, xv.x, fmaf(wi0b, xv.y, a0 + b0r));
            a1 += b1r;
            // in-register activation (per-lane gate type)
            float act0 = fmaf(rcpf_(1.f + __expf(kmul * a0)), kk, cc);
            float act1 = fmaf(rcpf_(1.f + __expf(kmul * a1)), kk, cc);
            // gather activated gates within the 8-lane unit group (src = base|2k)
            float i0 = SWZ(act0, 0x018), f0 = SWZ(act0, 0x058), g0 = SWZ(act0, 0x098), o0 = SWZ(act0, 0x0D8);
            float i1 = SWZ(act1, 0x018), f1 = SWZ(act1, 0x058), g1 = SWZ(act1, 0x098), o1 = SWZ(act1, 0x0D8);
            if (u < Tn) {
                c0 = fmaf(f0, c0, i0 * g0);
                float h0new = o0 * tanhf2_(c0);
                if (m == 0) h0s[par][j] = h0new;
            }
            if (u >= 1) {
                c1 = fmaf(f1, c1, i1 * g1);
                float h1new = o1 * tanhf2_(c1);
                if (m == 1) h1s[par ^ 1][j] = h1new;
                if (m == 2) h1ring[(u - 1) & (CH - 1)][j] = h1new;
                if (tid == 0) tempc[(u - 1) & (CH - 1)] = xprev;
            }
            xprev = xv.x;
        }
        __syncthreads();
    }
}

extern "C" void kernel_launch(void* const* d_in, const int* in_sizes, int n_in,
                              void* d_out, int out_size, void* d_ws, size_t ws_size,
                              hipStream_t stream) {
    const float* ts   = (const float*)d_in[0];
    const float* sf   = (const float*)d_in[1];
    const float* Wih0 = (const float*)d_in[2];
    const float* Whh0 = (const float*)d_in[3];
    const float* bih0 = (const float*)d_in[4];
    const float* bhh0 = (const float*)d_in[5];
    const float* Wih1 = (const float*)d_in[6];
    const float* Whh1 = (const float*)d_in[7];
    const float* bih1 = (const float*)d_in[8];
    const float* bhh1 = (const float*)d_in[9];
    const float* seW1 = (const float*)d_in[10];
    const float* seb1 = (const float*)d_in[11];
    const float* seW2 = (const float*)d_in[12];
    const float* seb2 = (const float*)d_in[13];
    const float* pbW1 = (const float*)d_in[14];
    const float* pbb1 = (const float*)d_in[15];
    const float* pbW2 = (const float*)d_in[16];
    const float* pbb2 = (const float*)d_in[17];
    const float* pbW3 = (const float*)d_in[18];
    const float* pbb3 = (const float*)d_in[19];
    const float* drW1 = (const float*)d_in[20];
    const float* drb1 = (const float*)d_in[21];
    const float* drW2 = (const float*)d_in[22];
    const float* drb2 = (const float*)d_in[23];
    const float* drW3 = (const float*)d_in[24];
    const float* drb3 = (const float*)d_in[25];
    const float* ruW1 = (const float*)d_in[26];
    const float* rub1 = (const float*)d_in[27];
    const float* ruW2 = (const float*)d_in[28];
    const float* rub2 = (const float*)d_in[29];
    float* out = (float*)d_out;

    fused_rul_kernel<<<dim3(Bn), dim3(NT), 0, stream>>>(
        ts, sf, Wih0, Whh0, bih0, bhh0, Wih1, Whh1, bih1, bhh1,
        seW1, seb1, seW2, seb2, pbW1, pbb1, pbW2, pbb2, pbW3, pbb3,
        drW1, drb1, drW2, drb2, drW3, drb3, ruW1, rub1, ruW2, rub2, out);
}